// Round 2
// baseline (203.134 us; speedup 1.0000x reference)
//
#include <hip/hip_runtime.h>
#include <math.h>

#define B_DIM 256
#define M_DIM 4096
#define EPSV 1e-7f
#define ROW_FLOATS (M_DIM * 9)     // 36864 floats per row
#define ROW_F4     (ROW_FLOATS / 4) // 9216 float4 per row (147456 B, 16B-aligned)
#define THREADS    1024
#define RECON_BLOCKS 256
#define GRID (B_DIM + RECON_BLOCKS)

// ws layout (doubles):
// 0: coord_num, 1: width_num, 2: validity_sum, 3: n_valid, 4: cont_sum,
// 5: recon_sum, 6: (as ull) completion counter

__global__ __launch_bounds__(1024) void fused_loss_kernel(
    const float* __restrict__ pred, const float* __restrict__ tgt,
    const float4* __restrict__ rec, const float4* __restrict__ img,
    double* __restrict__ ws, float* __restrict__ out)
{
    __shared__ float s_p4[M_DIM];                      // 16 KB
    __shared__ float s_p5[M_DIM];                      // 16 KB
    __shared__ unsigned long long s_words[M_DIM / 64]; // 512 B
    __shared__ float s_red[16][5];

    const int t    = threadIdx.x;
    const int lane = t & 63;
    const int wave = t >> 6;

    if (blockIdx.x >= B_DIM) {
        // ---- reconstruction MSE blocks ----
        const int n4     = (B_DIM * 128 * 128) / 4;      // 1048576
        const int stride = RECON_BLOCKS * THREADS;       // 262144
        int idx = (blockIdx.x - B_DIM) * THREADS + t;
        float s = 0.f;
        #pragma unroll
        for (int i = 0; i < 4; ++i) {                    // n4/stride == 4 exactly
            float4 r = rec[idx]; float4 m = img[idx];
            float d0 = r.x - m.x, d1 = r.y - m.y, d2 = r.z - m.z, d3 = r.w - m.w;
            s += d0 * d0 + d1 * d1 + d2 * d2 + d3 * d3;
            idx += stride;
        }
        #pragma unroll
        for (int off = 32; off > 0; off >>= 1) s += __shfl_down(s, off, 64);
        if (lane == 0) s_red[wave][0] = s;
        __syncthreads();
        if (t == 0) {
            float a = 0.f;
            for (int w = 0; w < 16; ++w) a += s_red[w][0];
            atomicAdd(&ws[5], (double)a);
        }
    } else {
        // ---- per-row loss blocks ----
        const int b = blockIdx.x;
        const float* prow = pred + (size_t)b * ROW_FLOATS;
        const float* trow = tgt  + (size_t)b * ROW_FLOATS;

        // Phase 1: validity bitmask + BCE + n_valid (strided component-8 loads;
        // side effect: prefetches every 64B line of both rows into L2).
        float val_s = 0.f, nval_s = 0.f;
        bool valid_k[4];
        #pragma unroll
        for (int k = 0; k < 4; ++k) {
            const int m = k * 1024 + t;
            float t8 = trow[m * 9 + 8];
            float p8 = prow[m * 9 + 8];
            bool valid = (t8 > 0.5f);
            valid_k[k] = valid;
            nval_s += valid ? 1.f : 0.f;
            float pc = fminf(fmaxf(p8, EPSV), 1.0f - EPSV);
            val_s += -(t8 * __logf(pc) + (1.0f - t8) * __logf(1.0f - pc));
            unsigned long long bal = __ballot(valid);
            if (lane == 0) s_words[k * 16 + wave] = bal;
        }
        __syncthreads();

        // Phase 2: coalesced float4 pass — coord/width masked L1 + p4/p5 staging.
        float coord_s = 0.f, width_s = 0.f;
        const float4* pf4 = (const float4*)prow;
        const float4* tf4 = (const float4*)trow;
        #pragma unroll
        for (int i = 0; i < ROW_F4 / THREADS; ++i) {     // 9 iters
            int f = i * THREADS + t;
            float4 pv = pf4[f];
            float4 tv = tf4[f];
            int j0 = f * 4;
            int m  = j0 / 9;
            int c  = j0 - m * 9;
            float pe[4] = {pv.x, pv.y, pv.z, pv.w};
            float te[4] = {tv.x, tv.y, tv.z, tv.w};
            #pragma unroll
            for (int k = 0; k < 4; ++k) {
                float fm = (float)((s_words[m >> 6] >> (m & 63)) & 1ULL);
                float ad = fabsf(pe[k] - te[k]);
                if (c < 6)      coord_s += fm * ad;
                else if (c < 8) width_s += fm * ad;
                if (c == 4)      s_p4[m] = pe[k];
                else if (c == 5) s_p5[m] = pe[k];
                ++c; if (c == 9) { c = 0; ++m; }
            }
        }
        __syncthreads();

        // Phase 3: continuity — next-valid-neighbor bit-scan in LDS.
        float cont_s = 0.f;
        #pragma unroll
        for (int k = 0; k < 4; ++k) {
            if (!valid_k[k]) continue;
            const int m   = k * 1024 + t;
            const int w   = m >> 6;
            const int bit = m & 63;
            unsigned long long mask = s_words[w];
            mask &= (bit == 63) ? 0ULL : (~0ULL << (bit + 1));
            int nxt = -1;
            if (mask) {
                nxt = (w << 6) + __builtin_ctzll(mask);
            } else {
                for (int w2 = w + 1; w2 < (M_DIM / 64); ++w2) {
                    unsigned long long mw = s_words[w2];
                    if (mw) { nxt = (w2 << 6) + __builtin_ctzll(mw); break; }
                }
            }
            if (nxt >= 0) {
                cont_s += 0.5f * (fabsf(s_p4[m] - s_p4[nxt]) +
                                  fabsf(s_p5[m] - s_p5[nxt]));
            }
        }

        // Block reduction of 5 partials.
        float vals[5] = {coord_s, width_s, val_s, nval_s, cont_s};
        #pragma unroll
        for (int i = 0; i < 5; ++i) {
            float v = vals[i];
            #pragma unroll
            for (int off = 32; off > 0; off >>= 1) v += __shfl_down(v, off, 64);
            vals[i] = v;
        }
        if (lane == 0) {
            #pragma unroll
            for (int i = 0; i < 5; ++i) s_red[wave][i] = vals[i];
        }
        __syncthreads();
        if (t == 0) {
            float acc[5] = {0.f, 0.f, 0.f, 0.f, 0.f};
            for (int wv = 0; wv < 16; ++wv)
                #pragma unroll
                for (int i = 0; i < 5; ++i) acc[i] += s_red[wv][i];
            atomicAdd(&ws[0], (double)acc[0]);
            atomicAdd(&ws[1], (double)acc[1]);
            atomicAdd(&ws[2], (double)acc[2]);
            atomicAdd(&ws[3], (double)acc[3]);
            atomicAdd(&ws[4], (double)acc[4]);
        }
    }

    // ---- last-block finalize (saves a kernel launch) ----
    __syncthreads();
    if (t == 0) {
        __threadfence();
        unsigned long long* cnt = (unsigned long long*)&ws[6];
        unsigned long long old = atomicAdd(cnt, 1ULL);
        if (old == (unsigned long long)(GRID - 1)) {
            __threadfence();
            // atomic reads (add 0) to guarantee device-scope coherent values
            double coord_num = atomicAdd(&ws[0], 0.0);
            double width_num = atomicAdd(&ws[1], 0.0);
            double val_sum   = atomicAdd(&ws[2], 0.0);
            double nv        = atomicAdd(&ws[3], 0.0);
            double cont      = atomicAdd(&ws[4], 0.0);
            double recon     = atomicAdd(&ws[5], 0.0);

            double coord = (nv > 0.0) ? coord_num / fmax(nv * 6.0, 1.0) : 0.0;
            double width = (nv > 0.0) ? width_num / fmax(nv * 2.0, 1.0) : 0.0;
            double validity = val_sum / ((double)B_DIM * (double)M_DIM);
            double contl    = cont / (double)B_DIM;
            double reconl   = recon / ((double)B_DIM * 128.0 * 128.0);

            out[0] = (float)(coord + width + 2.0 * validity +
                             0.2 * contl + 0.1 * reconl);
        }
    }
}

extern "C" void kernel_launch(void* const* d_in, const int* in_sizes, int n_in,
                              void* d_out, int out_size, void* d_ws, size_t ws_size,
                              hipStream_t stream) {
    const float* pred = (const float*)d_in[0];
    const float* tgt  = (const float*)d_in[1];
    const float* rec  = (const float*)d_in[2];
    const float* img  = (const float*)d_in[3];
    double* ws = (double*)d_ws;

    hipMemsetAsync(d_ws, 0, 7 * sizeof(double), stream);

    fused_loss_kernel<<<GRID, THREADS, 0, stream>>>(
        pred, tgt, (const float4*)rec, (const float4*)img, ws, (float*)d_out);
}